// Round 3
// baseline (5234.924 us; speedup 1.0000x reference)
//
#include <hip/hip_runtime.h>
#include <hip/hip_bf16.h>
#include <math.h>

// Problem dims
#define B_  32
#define T_  512
#define D_  128
#define N_  1024
#define NOISE_ 0.001f

#define NBLK 64           // recurrence blocks; each owns N_/NBLK = 16 columns
#define CPB  16           // columns per block

typedef __attribute__((ext_vector_type(8))) short  bf16x8;
typedef __attribute__((ext_vector_type(4))) float  f32x4;

static __device__ __forceinline__ unsigned short f2bf_rn(float f) {
    unsigned int u = __builtin_bit_cast(unsigned int, f);
    unsigned int r = (u + 0x7FFFu + ((u >> 16) & 1u)) >> 16;
    return (unsigned short)r;
}
static __device__ __forceinline__ float bf2f(unsigned short h) {
    return __builtin_bit_cast(float, (unsigned int)h << 16);
}

// ---------------------------------------------------------------------------
// Kernel A: xin = (x @ w_input) * scale, written INTO d_out at [b][t][n].
// ---------------------------------------------------------------------------
__global__ __launch_bounds__(256) void xin_gemm(
    const float* __restrict__ x, const float* __restrict__ w_in,
    const float* __restrict__ scale_p, float* __restrict__ out) {
  __shared__ float As[64 * 132];
  __shared__ float Bs[128 * 68];
  const int tid = threadIdx.x;
  const int bm = blockIdx.x;       // 0..255
  const int bn = blockIdx.y;       // 0..15

  {
    const f32x4* xg = (const f32x4*)(x + (size_t)bm * 64 * 128);
#pragma unroll
    for (int i = 0; i < 8; ++i) {
      int idx = tid + i * 256;
      int r = idx >> 5, c4 = idx & 31;
      f32x4 v = xg[idx];
      float* dst = &As[r * 132 + c4 * 4];
      dst[0] = v.x; dst[1] = v.y; dst[2] = v.z; dst[3] = v.w;
    }
  }
  {
#pragma unroll
    for (int i = 0; i < 8; ++i) {
      int idx = tid + i * 256;
      int r = idx >> 4, c4 = idx & 15;
      f32x4 v = *(const f32x4*)(w_in + (size_t)r * N_ + bn * 64 + c4 * 4);
      float* dst = &Bs[r * 68 + c4 * 4];
      dst[0] = v.x; dst[1] = v.y; dst[2] = v.z; dst[3] = v.w;
    }
  }
  __syncthreads();

  const int tx = tid & 15, ty = tid >> 4;
  float acc[4][4] = {};
  for (int k = 0; k < 128; ++k) {
    float a0 = As[(ty * 4 + 0) * 132 + k];
    float a1 = As[(ty * 4 + 1) * 132 + k];
    float a2 = As[(ty * 4 + 2) * 132 + k];
    float a3 = As[(ty * 4 + 3) * 132 + k];
    f32x4 bv = *(const f32x4*)&Bs[k * 68 + tx * 4];
#pragma unroll
    for (int j = 0; j < 4; ++j) {
      acc[0][j] += a0 * bv[j];
      acc[1][j] += a1 * bv[j];
      acc[2][j] += a2 * bv[j];
      acc[3][j] += a3 * bv[j];
    }
  }
  const float s = scale_p[0];
#pragma unroll
  for (int i = 0; i < 4; ++i) {
    int row = bm * 64 + ty * 4 + i;
    if ((row & 511) == 0) continue;
    f32x4 o;
    o.x = acc[i][0] * s; o.y = acc[i][1] * s;
    o.z = acc[i][2] * s; o.w = acc[i][3] * s;
    *(f32x4*)(out + (size_t)row * N_ + bn * 64 + tx * 4) = o;
  }
}

// ---------------------------------------------------------------------------
// Kernel B: out[:,0,:] = step0 ; states0 -> compensated bf16 ping buffer 0 ;
// zero per-wave flags (256 used).
// ---------------------------------------------------------------------------
__global__ __launch_bounds__(256) void init_k(
    const float* __restrict__ states0, const float* __restrict__ step0,
    float* __restrict__ out, unsigned short* __restrict__ st_hi,
    unsigned short* __restrict__ st_lo, int* __restrict__ flags) {
  int i = blockIdx.x * 256 + threadIdx.x;
  if (i < B_ * N_) {
    int b = i >> 10, n = i & 1023;
    out[((size_t)b * T_ + 0) * N_ + n] = step0[i];
    float sv = states0[i];
    unsigned short h = f2bf_rn(sv);
    st_hi[i] = h;
    st_lo[i] = f2bf_rn(sv - bf2f(h));
  }
  if (i < 1024) flags[i] = 0;
}

// ---------------------------------------------------------------------------
// Kernel C: persistent recurrence. 64 blocks x 256 threads.
// Per-WAVE flag publish (wave-level vmcnt drain + relaxed system store) and
// per-wave parallel poll of all 256 wave-flags; per-wave acquire fence; no
// __syncthreads on the inter-block chain (poll doubles as intra-block WAR
// barrier for pLDS / state ping-pong at distance 2). All 32 A-fragments
// preloaded into registers for max MLP on the L3-latency broadcast loads.
// ---------------------------------------------------------------------------
__global__ __launch_bounds__(256, 1) void esn_rec(
    const float* __restrict__ w_res, const float* __restrict__ rn,
    float* __restrict__ out, unsigned short* __restrict__ st_hi,
    unsigned short* __restrict__ st_lo, int* flags) {
  __shared__ bf16x8 wHi8[CPB * 129];
  __shared__ bf16x8 wLo8[CPB * 129];
  __shared__ float  pLDS[4 * 32 * 17];   // [wave][m(32)][c(16)] pad 17

  const int tid = threadIdx.x;
  const int blk = blockIdx.x;

  // one-time: load + split w_res column slice into LDS (compensated bf16)
  {
    unsigned short* wH = (unsigned short*)wHi8;
    unsigned short* wL = (unsigned short*)wLo8;
    for (int i = tid; i < CPB * 1024; i += 256) {
      int c = i & 15, k = i >> 4;
      float wv = w_res[(size_t)k * N_ + blk * CPB + c];
      unsigned short h = f2bf_rn(wv);
      wH[c * 1032 + k] = h;
      wL[c * 1032 + k] = f2bf_rn(wv - bf2f(h));
    }
  }
  __syncthreads();

  const int lane = tid & 63, wave = tid >> 6;
  const int quad = lane >> 4, lm = lane & 15;
  const int kc8 = wave * 32;             // wave's K-chunk base, short8 units

  // epilogue mapping: thread owns (row rm, cols cp, cp+1)
  const int rm = tid >> 3;               // 0..31
  const int cp = (tid & 7) * 2;          // 0,2,..,14
  const int colg = blk * CPB + cp;
  float2 nz = *(const float2*)&rn[(size_t)rm * N_ + colg];
  nz.x *= NOISE_; nz.y *= NOISE_;

  for (int t = 1; t < T_; ++t) {
    const int pc = (t - 1) & 1, ncur = t & 1;

    // prefetch xin (own slot; written by xin_gemm, read+overwritten by us)
    size_t o0 = ((size_t)rm * T_ + t) * N_ + colg;
    float2 xv = *(const float2*)&out[o0];

    // poll all 256 wave-flags (every wave does this; 4 loads/lane)
    {
      const int need = t - 1;
      while (true) {
        int f0 = __hip_atomic_load(&flags[lane * 4 + 0], __ATOMIC_RELAXED,
                                   __HIP_MEMORY_SCOPE_SYSTEM);
        int f1 = __hip_atomic_load(&flags[lane * 4 + 1], __ATOMIC_RELAXED,
                                   __HIP_MEMORY_SCOPE_SYSTEM);
        int f2 = __hip_atomic_load(&flags[lane * 4 + 2], __ATOMIC_RELAXED,
                                   __HIP_MEMORY_SCOPE_SYSTEM);
        int f3 = __hip_atomic_load(&flags[lane * 4 + 3], __ATOMIC_RELAXED,
                                   __HIP_MEMORY_SCOPE_SYSTEM);
        bool ok = (f0 >= need) & (f1 >= need) & (f2 >= need) & (f3 >= need);
        if (__all(ok)) break;
      }
    }
    __builtin_amdgcn_fence(__ATOMIC_ACQUIRE, "agent");   // buffer_inv (per wave)

    const bf16x8* sh8 = (const bf16x8*)(st_hi + pc * (B_ * N_));
    const bf16x8* sl8 = (const bf16x8*)(st_lo + pc * (B_ * N_));

    // preload ALL 32 A-fragments (max loads-in-flight)
    bf16x8 AH0[8], AH1[8], AL0[8], AL1[8];
#pragma unroll
    for (int kk = 0; kk < 8; ++kk) {
      const int k8 = kc8 + kk * 4 + quad;
      AH0[kk] = sh8[lm * 128 + k8];
      AH1[kk] = sh8[(lm + 16) * 128 + k8];
      AL0[kk] = sl8[lm * 128 + k8];
      AL1[kk] = sl8[(lm + 16) * 128 + k8];
    }

    f32x4 acc0 = {0.f, 0.f, 0.f, 0.f};
    f32x4 acc1 = {0.f, 0.f, 0.f, 0.f};
#pragma unroll
    for (int kk = 0; kk < 8; ++kk) {
      const int k8 = kc8 + kk * 4 + quad;
      bf16x8 bh = wHi8[lm * 129 + k8];
      bf16x8 bl = wLo8[lm * 129 + k8];
      acc0 = __builtin_amdgcn_mfma_f32_16x16x32_bf16(AH0[kk], bh, acc0, 0, 0, 0);
      acc1 = __builtin_amdgcn_mfma_f32_16x16x32_bf16(AH1[kk], bh, acc1, 0, 0, 0);
      acc0 = __builtin_amdgcn_mfma_f32_16x16x32_bf16(AL0[kk], bh, acc0, 0, 0, 0);
      acc1 = __builtin_amdgcn_mfma_f32_16x16x32_bf16(AL1[kk], bh, acc1, 0, 0, 0);
      acc0 = __builtin_amdgcn_mfma_f32_16x16x32_bf16(AH0[kk], bl, acc0, 0, 0, 0);
      acc1 = __builtin_amdgcn_mfma_f32_16x16x32_bf16(AH1[kk], bl, acc1, 0, 0, 0);
    }

    // write K-partials: C frag layout row=quad*4+r, col=lm
#pragma unroll
    for (int r = 0; r < 4; ++r) {
      pLDS[wave * 544 + (quad * 4 + r) * 17 + lm]      = acc0[r];
      pLDS[wave * 544 + (quad * 4 + r + 16) * 17 + lm] = acc1[r];
    }
    __syncthreads();

    // reduce 4 K-partials for (rm, cp) and (rm, cp+1)
    float sa = pLDS[0 * 544 + rm * 17 + cp] + pLDS[1 * 544 + rm * 17 + cp]
             + pLDS[2 * 544 + rm * 17 + cp] + pLDS[3 * 544 + rm * 17 + cp];
    float sb = pLDS[0 * 544 + rm * 17 + cp + 1] + pLDS[1 * 544 + rm * 17 + cp + 1]
             + pLDS[2 * 544 + rm * 17 + cp + 1] + pLDS[3 * 544 + rm * 17 + cp + 1];
    float v0 = tanhf(sa + xv.x) + nz.x;
    float v1 = tanhf(sb + xv.y) + nz.y;
    float2 ov; ov.x = v0; ov.y = v1;
    *(float2*)&out[o0] = ov;

    // publish compensated bf16 state: write-through system stores
    unsigned short h0 = f2bf_rn(v0), h1 = f2bf_rn(v1);
    unsigned short l0 = f2bf_rn(v0 - bf2f(h0)), l1 = f2bf_rn(v1 - bf2f(h1));
    unsigned int hpack = (unsigned int)h0 | ((unsigned int)h1 << 16);
    unsigned int lpack = (unsigned int)l0 | ((unsigned int)l1 << 16);
    unsigned int* dh = (unsigned int*)(st_hi + ncur * (B_ * N_) + (size_t)rm * N_ + colg);
    unsigned int* dl = (unsigned int*)(st_lo + ncur * (B_ * N_) + (size_t)rm * N_ + colg);
    __hip_atomic_store(dh, hpack, __ATOMIC_RELAXED, __HIP_MEMORY_SCOPE_SYSTEM);
    __hip_atomic_store(dl, lpack, __ATOMIC_RELAXED, __HIP_MEMORY_SCOPE_SYSTEM);

    // per-wave release: drain THIS wave's store acks, then publish wave flag
    asm volatile("s_waitcnt vmcnt(0)" ::: "memory");
    if (lane == 0) {
      __hip_atomic_store(&flags[blk * 4 + wave], t, __ATOMIC_RELAXED,
                         __HIP_MEMORY_SCOPE_SYSTEM);
    }
  }
}

// ---------------------------------------------------------------------------
extern "C" void kernel_launch(void* const* d_in, const int* in_sizes, int n_in,
                              void* d_out, int out_size, void* d_ws, size_t ws_size,
                              hipStream_t stream) {
  const float* x       = (const float*)d_in[0];
  const float* w_in    = (const float*)d_in[1];
  const float* w_res   = (const float*)d_in[2];
  const float* wscale  = (const float*)d_in[3];
  const float* states0 = (const float*)d_in[4];
  const float* step0   = (const float*)d_in[5];
  const float* rnoise  = (const float*)d_in[6];
  float* out = (float*)d_out;

  char* ws = (char*)d_ws;
  unsigned short* st_hi = (unsigned short*)ws;                 // 131072 B
  unsigned short* st_lo = (unsigned short*)(ws + 131072);      // 131072 B
  int* flags            = (int*)(ws + 262144);                 // 4096 B

  xin_gemm<<<dim3(256, 16), 256, 0, stream>>>(x, w_in, wscale, out);
  init_k<<<128, 256, 0, stream>>>(states0, step0, out, st_hi, st_lo, flags);
  esn_rec<<<NBLK, 256, 0, stream>>>(w_res, rnoise, out, st_hi, st_lo, flags);
}

// Round 4
// 3142.435 us; speedup vs baseline: 1.6659x; 1.6659x over previous
//
#include <hip/hip_runtime.h>
#include <hip/hip_bf16.h>
#include <math.h>

// Problem dims
#define B_  32
#define T_  512
#define D_  128
#define N_  1024
#define NOISE_ 0.001f

#define NBLK 64           // recurrence blocks; each owns N_/NBLK = 16 columns
#define CPB  16           // columns per block

typedef __attribute__((ext_vector_type(8))) short  bf16x8;
typedef __attribute__((ext_vector_type(4))) float  f32x4;

static __device__ __forceinline__ unsigned short f2bf_rn(float f) {
    unsigned int u = __builtin_bit_cast(unsigned int, f);
    unsigned int r = (u + 0x7FFFu + ((u >> 16) & 1u)) >> 16;
    return (unsigned short)r;
}
static __device__ __forceinline__ float bf2f(unsigned short h) {
    return __builtin_bit_cast(float, (unsigned int)h << 16);
}

// ---------------------------------------------------------------------------
// Kernel A: xin = (x @ w_input) * scale, written INTO d_out at [b][t][n].
// ---------------------------------------------------------------------------
__global__ __launch_bounds__(256) void xin_gemm(
    const float* __restrict__ x, const float* __restrict__ w_in,
    const float* __restrict__ scale_p, float* __restrict__ out) {
  __shared__ float As[64 * 132];
  __shared__ float Bs[128 * 68];
  const int tid = threadIdx.x;
  const int bm = blockIdx.x;       // 0..255
  const int bn = blockIdx.y;       // 0..15

  {
    const f32x4* xg = (const f32x4*)(x + (size_t)bm * 64 * 128);
#pragma unroll
    for (int i = 0; i < 8; ++i) {
      int idx = tid + i * 256;
      int r = idx >> 5, c4 = idx & 31;
      f32x4 v = xg[idx];
      float* dst = &As[r * 132 + c4 * 4];
      dst[0] = v.x; dst[1] = v.y; dst[2] = v.z; dst[3] = v.w;
    }
  }
  {
#pragma unroll
    for (int i = 0; i < 8; ++i) {
      int idx = tid + i * 256;
      int r = idx >> 4, c4 = idx & 15;
      f32x4 v = *(const f32x4*)(w_in + (size_t)r * N_ + bn * 64 + c4 * 4);
      float* dst = &Bs[r * 68 + c4 * 4];
      dst[0] = v.x; dst[1] = v.y; dst[2] = v.z; dst[3] = v.w;
    }
  }
  __syncthreads();

  const int tx = tid & 15, ty = tid >> 4;
  float acc[4][4] = {};
  for (int k = 0; k < 128; ++k) {
    float a0 = As[(ty * 4 + 0) * 132 + k];
    float a1 = As[(ty * 4 + 1) * 132 + k];
    float a2 = As[(ty * 4 + 2) * 132 + k];
    float a3 = As[(ty * 4 + 3) * 132 + k];
    f32x4 bv = *(const f32x4*)&Bs[k * 68 + tx * 4];
#pragma unroll
    for (int j = 0; j < 4; ++j) {
      acc[0][j] += a0 * bv[j];
      acc[1][j] += a1 * bv[j];
      acc[2][j] += a2 * bv[j];
      acc[3][j] += a3 * bv[j];
    }
  }
  const float s = scale_p[0];
#pragma unroll
  for (int i = 0; i < 4; ++i) {
    int row = bm * 64 + ty * 4 + i;
    if ((row & 511) == 0) continue;
    f32x4 o;
    o.x = acc[i][0] * s; o.y = acc[i][1] * s;
    o.z = acc[i][2] * s; o.w = acc[i][3] * s;
    *(f32x4*)(out + (size_t)row * N_ + bn * 64 + tx * 4) = o;
  }
}

// ---------------------------------------------------------------------------
// Kernel B: out[:,0,:] = step0 ; states0 -> compensated bf16 ping buffer 0 ;
// zero per-block flags.
// ---------------------------------------------------------------------------
__global__ __launch_bounds__(256) void init_k(
    const float* __restrict__ states0, const float* __restrict__ step0,
    float* __restrict__ out, unsigned short* __restrict__ st_hi,
    unsigned short* __restrict__ st_lo, int* __restrict__ flags) {
  int i = blockIdx.x * 256 + threadIdx.x;
  if (i < B_ * N_) {
    int b = i >> 10, n = i & 1023;
    out[((size_t)b * T_ + 0) * N_ + n] = step0[i];
    float sv = states0[i];
    unsigned short h = f2bf_rn(sv);
    st_hi[i] = h;
    st_lo[i] = f2bf_rn(sv - bf2f(h));
  }
  if (i < 1024) flags[i] = 0;   // 64 flags at 16-int (64 B) stride
}

// ---------------------------------------------------------------------------
// Kernel C: persistent recurrence. 64 blocks x 256 threads.
// R2 skeleton + (a) state loads via hand-issued global_load_dwordx4 sc0 sc1
// (coherence-point reads -> no acquire fence / no buffer_inv; forced MLP:
// all 32 fragment loads in flight before one vmcnt(0)); (b) each wave waits
// only on its 16 producer blocks and proceeds independently (epilogue still
// behind the block barrier, whose 4-wave union re-establishes the all-64
// guarantee needed for double-buffer WAR safety).
// ---------------------------------------------------------------------------
__global__ __launch_bounds__(256, 1) void esn_rec(
    const float* __restrict__ w_res, const float* __restrict__ rn,
    float* __restrict__ out, unsigned short* __restrict__ st_hi,
    unsigned short* __restrict__ st_lo, int* flags) {
  __shared__ bf16x8 wHi8[CPB * 129];
  __shared__ bf16x8 wLo8[CPB * 129];
  __shared__ float  pLDS[4 * 32 * 17];   // [wave][m(32)][c(16)] pad 17

  const int tid = threadIdx.x;
  const int blk = blockIdx.x;

  // one-time: load + split w_res column slice into LDS (compensated bf16)
  {
    unsigned short* wH = (unsigned short*)wHi8;
    unsigned short* wL = (unsigned short*)wLo8;
    for (int i = tid; i < CPB * 1024; i += 256) {
      int c = i & 15, k = i >> 4;
      float wv = w_res[(size_t)k * N_ + blk * CPB + c];
      unsigned short h = f2bf_rn(wv);
      wH[c * 1032 + k] = h;
      wL[c * 1032 + k] = f2bf_rn(wv - bf2f(h));
    }
  }
  __syncthreads();

  const int lane = tid & 63, wave = tid >> 6;
  const int quad = lane >> 4, lm = lane & 15;

  // epilogue mapping: thread owns (row rm, cols cp, cp+1)
  const int rm = tid >> 3;               // 0..31
  const int cp = (tid & 7) * 2;          // 0,2,..,14
  const int colg = blk * CPB + cp;
  float2 nz = *(const float2*)&rn[(size_t)rm * N_ + colg];
  nz.x *= NOISE_; nz.y *= NOISE_;

  // byte voffsets for the wave's state fragments (row lm and lm+16)
  const int vo0 = lm * 2048 + wave * 512 + quad * 16;
  const int vo1 = vo0 + 16 * 2048;

  for (int t = 1; t < T_; ++t) {
    const int pc = (t - 1) & 1, ncur = t & 1;

    // prefetch xin (own slot; written by xin_gemm, read+overwritten by us)
    size_t o0 = ((size_t)rm * T_ + t) * N_ + colg;
    float2 xv = *(const float2*)&out[o0];

    // per-wave poll: wave w needs only producer blocks 16w..16w+15
    {
      const int need = t - 1;
      const int fidx = (wave * 16 + (lane & 15)) * 16;
      while (true) {
        int f = __hip_atomic_load(&flags[fidx], __ATOMIC_RELAXED,
                                  __HIP_MEMORY_SCOPE_SYSTEM);
        if (__all(f >= need)) break;
      }
    }

    // state fragment loads: coherence-point reads, hand-issued, full MLP
    const char* baseH = (const char*)(st_hi + pc * (B_ * N_));
    const char* baseL = (const char*)(st_lo + pc * (B_ * N_));
    bf16x8 AH0[8], AH1[8], AL0[8], AL1[8];
#pragma unroll
    for (int kk = 0; kk < 8; ++kk) {
      int oa = vo0 + kk * 64, ob = vo1 + kk * 64;
      asm volatile("global_load_dwordx4 %0, %1, %2 sc0 sc1"
                   : "=v"(AH0[kk]) : "v"(oa), "s"(baseH) : "memory");
      asm volatile("global_load_dwordx4 %0, %1, %2 sc0 sc1"
                   : "=v"(AH1[kk]) : "v"(ob), "s"(baseH) : "memory");
      asm volatile("global_load_dwordx4 %0, %1, %2 sc0 sc1"
                   : "=v"(AL0[kk]) : "v"(oa), "s"(baseL) : "memory");
      asm volatile("global_load_dwordx4 %0, %1, %2 sc0 sc1"
                   : "=v"(AL1[kk]) : "v"(ob), "s"(baseL) : "memory");
    }
    asm volatile("s_waitcnt vmcnt(0)" ::: "memory");

    f32x4 acc0 = {0.f, 0.f, 0.f, 0.f};
    f32x4 acc1 = {0.f, 0.f, 0.f, 0.f};
#pragma unroll
    for (int kk = 0; kk < 8; ++kk) {
      const int k8 = wave * 32 + kk * 4 + quad;
      bf16x8 bh = wHi8[lm * 129 + k8];
      bf16x8 bl = wLo8[lm * 129 + k8];
      acc0 = __builtin_amdgcn_mfma_f32_16x16x32_bf16(AH0[kk], bh, acc0, 0, 0, 0);
      acc1 = __builtin_amdgcn_mfma_f32_16x16x32_bf16(AH1[kk], bh, acc1, 0, 0, 0);
      acc0 = __builtin_amdgcn_mfma_f32_16x16x32_bf16(AL0[kk], bh, acc0, 0, 0, 0);
      acc1 = __builtin_amdgcn_mfma_f32_16x16x32_bf16(AL1[kk], bh, acc1, 0, 0, 0);
      acc0 = __builtin_amdgcn_mfma_f32_16x16x32_bf16(AH0[kk], bl, acc0, 0, 0, 0);
      acc1 = __builtin_amdgcn_mfma_f32_16x16x32_bf16(AH1[kk], bl, acc1, 0, 0, 0);
    }

    // write K-partials: C frag layout row=quad*4+r, col=lm
#pragma unroll
    for (int r = 0; r < 4; ++r) {
      pLDS[wave * 544 + (quad * 4 + r) * 17 + lm]      = acc0[r];
      pLDS[wave * 544 + (quad * 4 + r + 16) * 17 + lm] = acc1[r];
    }
    __syncthreads();

    // reduce 4 K-partials for (rm, cp) and (rm, cp+1)
    float sa = pLDS[0 * 544 + rm * 17 + cp] + pLDS[1 * 544 + rm * 17 + cp]
             + pLDS[2 * 544 + rm * 17 + cp] + pLDS[3 * 544 + rm * 17 + cp];
    float sb = pLDS[0 * 544 + rm * 17 + cp + 1] + pLDS[1 * 544 + rm * 17 + cp + 1]
             + pLDS[2 * 544 + rm * 17 + cp + 1] + pLDS[3 * 544 + rm * 17 + cp + 1];
    float v0 = tanhf(sa + xv.x) + nz.x;
    float v1 = tanhf(sb + xv.y) + nz.y;
    float2 ov; ov.x = v0; ov.y = v1;
    *(float2*)&out[o0] = ov;

    // publish compensated bf16 state: write-through system stores
    unsigned short h0 = f2bf_rn(v0), h1 = f2bf_rn(v1);
    unsigned short l0 = f2bf_rn(v0 - bf2f(h0)), l1 = f2bf_rn(v1 - bf2f(h1));
    unsigned int hpack = (unsigned int)h0 | ((unsigned int)h1 << 16);
    unsigned int lpack = (unsigned int)l0 | ((unsigned int)l1 << 16);
    unsigned int* dh = (unsigned int*)(st_hi + ncur * (B_ * N_) + (size_t)rm * N_ + colg);
    unsigned int* dl = (unsigned int*)(st_lo + ncur * (B_ * N_) + (size_t)rm * N_ + colg);
    __hip_atomic_store(dh, hpack, __ATOMIC_RELAXED, __HIP_MEMORY_SCOPE_SYSTEM);
    __hip_atomic_store(dl, lpack, __ATOMIC_RELAXED, __HIP_MEMORY_SCOPE_SYSTEM);

    // explicit per-thread drain, block barrier, then tid0 posts block flag
    asm volatile("s_waitcnt vmcnt(0)" ::: "memory");
    __syncthreads();
    if (tid == 0) {
      __hip_atomic_store(&flags[blk * 16], t, __ATOMIC_RELAXED,
                         __HIP_MEMORY_SCOPE_SYSTEM);
    }
  }
}

// ---------------------------------------------------------------------------
extern "C" void kernel_launch(void* const* d_in, const int* in_sizes, int n_in,
                              void* d_out, int out_size, void* d_ws, size_t ws_size,
                              hipStream_t stream) {
  const float* x       = (const float*)d_in[0];
  const float* w_in    = (const float*)d_in[1];
  const float* w_res   = (const float*)d_in[2];
  const float* wscale  = (const float*)d_in[3];
  const float* states0 = (const float*)d_in[4];
  const float* step0   = (const float*)d_in[5];
  const float* rnoise  = (const float*)d_in[6];
  float* out = (float*)d_out;

  char* ws = (char*)d_ws;
  unsigned short* st_hi = (unsigned short*)ws;                 // 131072 B
  unsigned short* st_lo = (unsigned short*)(ws + 131072);      // 131072 B
  int* flags            = (int*)(ws + 262144);                 // 4096 B

  xin_gemm<<<dim3(256, 16), 256, 0, stream>>>(x, w_in, wscale, out);
  init_k<<<128, 256, 0, stream>>>(states0, step0, out, st_hi, st_lo, flags);
  esn_rec<<<NBLK, 256, 0, stream>>>(w_res, rnoise, out, st_hi, st_lo, flags);
}